// Round 1
// 1225.308 us; speedup vs baseline: 1.0075x; 1.0075x over previous
//
#include <hip/hip_runtime.h>
#include <math.h>

#define N_NODES 100000
#define N_EDGES 3200000
#define DIM 256
#define SCAN_B 1024
#define SCAN_NBLK ((N_NODES + SCAN_B - 1) / SCAN_B)  // 98
#define NPASS 8
#define WIN ((N_NODES + NPASS - 1) / NPASS)  // 12500

typedef unsigned short u16;
typedef unsigned int u32;
typedef __attribute__((ext_vector_type(8))) short bf16x8;
typedef __attribute__((ext_vector_type(4))) float f32x4;

__device__ __forceinline__ float bf2f(u16 u) {
    union { u32 i; float f; } v; v.i = ((u32)u) << 16; return v.f;
}
__device__ __forceinline__ u16 f2bf(float f) {
    union { float f; u32 i; } v; v.f = f;
    u32 x = v.i;
    return (u16)((x + 0x7fffu + ((x >> 16) & 1u)) >> 16);
}
__device__ __forceinline__ float sane(float v) {
    union { float f; u32 i; } u; u.f = v;
    if ((u.i & 0x7f800000u) == 0x7f800000u) return 0.f;
    return v;
}
__device__ __forceinline__ int iclamp(int v, int lo, int hi) {
    return v < lo ? lo : (v > hi ? hi : v);
}
// one dword holding 2 bf16 -> float2 (lo elem, hi elem)
__device__ __forceinline__ float2 cvt2(u32 d) {
    union { u32 i; float f; } lo, hi;
    lo.i = d << 16;
    hi.i = d & 0xffff0000u;
    return make_float2(lo.f, hi.f);
}

// ---- runtime format probes ----------------------------------------------
// flags[0]: 1 => float tensors are fp32, 0 => bf16
// flags[1]: 1 => edge_index is int64 (lo/hi word pairs), 0 => int32
__global__ void detect_kernel(const u32* __restrict__ xw_words,
                              const int* __restrict__ ei, int* __restrict__ flags) {
    int lane = threadIdx.x;
    int cnt = 0;
#pragma unroll
    for (int j = 0; j < 4; ++j) {
        u32 e = (xw_words[lane + 64 * j] >> 7) & 0xffu;
        cnt += (e >= 0x70 && e <= 0x88) ? 1 : 0;
    }
    int nz = 0;
#pragma unroll
    for (int j = 0; j < 4; ++j) nz += (ei[2 * (lane + 64 * j) + 1] != 0) ? 1 : 0;
#pragma unroll
    for (int off = 32; off; off >>= 1) {
        cnt += __shfl_down(cnt, off, 64);
        nz += __shfl_down(nz, off, 64);
    }
    if (lane == 0) {
        flags[0] = (cnt < 128) ? 1 : 0;
        flags[1] = (nz == 0) ? 1 : 0;
    }
}

__device__ __forceinline__ int edge_val(const int* __restrict__ ei, int which,
                                        int i, int f64) {
    long long idx = (long long)which * N_EDGES + i;
    int v = f64 ? ei[idx * 2] : ei[idx];
    return iclamp(v, 0, N_NODES - 1);
}

// ---- canonicalize x to internal bf16 ------------------------------------
__global__ void convert_x(const void* __restrict__ xin, u16* __restrict__ xbf,
                          const int* __restrict__ flags) {
    long long i = (long long)blockIdx.x * blockDim.x + threadIdx.x;
    if (i >= (long long)N_NODES * DIM) return;
    float v = flags[0] ? ((const float*)xin)[i] : bf2f(((const u16*)xin)[i]);
    xbf[i] = f2bf(sane(v));
}

// ---- CSR build: count + int32 conversion fused --------------------------
__global__ void count_convert(const int* __restrict__ ei, int* __restrict__ rowcount,
                              int* __restrict__ src32, int* __restrict__ dst32,
                              const int* __restrict__ flags) {
    int i = blockIdx.x * blockDim.x + threadIdx.x;
    if (i < N_EDGES) {
        int f = flags[1];
        int s = edge_val(ei, 0, i, f);
        int d = edge_val(ei, 1, i, f);
        src32[i] = s;
        dst32[i] = d;
        atomicAdd(&rowcount[d], 1);
    }
}

__global__ void compute_dis(const int* __restrict__ rowcount, float* __restrict__ dis) {
    int i = blockIdx.x * blockDim.x + threadIdx.x;
    if (i < N_NODES) {
        int c = iclamp(rowcount[i], 0, N_EDGES);
        dis[i] = rsqrtf((float)(c + 1));  // +1 self loop
    }
}

// ---- parallel 3-phase exclusive scan ------------------------------------
__global__ __launch_bounds__(SCAN_B) void scan_block_sums(const int* __restrict__ cnt,
                                                          int* __restrict__ bsum) {
    __shared__ int ws[16];
    int i = blockIdx.x * SCAN_B + threadIdx.x;
    int v = (i < N_NODES) ? cnt[i] : 0;
#pragma unroll
    for (int off = 32; off; off >>= 1) v += __shfl_down(v, off, 64);
    if ((threadIdx.x & 63) == 0) ws[threadIdx.x >> 6] = v;
    __syncthreads();
    if (threadIdx.x < 16) {
        int t = ws[threadIdx.x];
#pragma unroll
        for (int off = 8; off; off >>= 1) t += __shfl_down(t, off, 16);
        if (threadIdx.x == 0) bsum[blockIdx.x] = t;
    }
}

__global__ void scan_bsum(int* __restrict__ bsum, int* __restrict__ rowptr) {
    __shared__ int sdata[128];
    int i = threadIdx.x;  // 128 threads
    int v = (i < SCAN_NBLK) ? bsum[i] : 0;
    sdata[i] = v;
    __syncthreads();
    for (int off = 1; off < 128; off <<= 1) {
        int t = (i >= off) ? sdata[i - off] : 0;
        __syncthreads();
        sdata[i] += t;
        __syncthreads();
    }
    if (i < SCAN_NBLK) bsum[i] = sdata[i] - v;  // exclusive
    if (i == 0) rowptr[N_NODES] = sdata[127];   // total = E
}

__global__ __launch_bounds__(SCAN_B) void scan_final(const int* __restrict__ cnt,
                                                     const int* __restrict__ bsum,
                                                     int* __restrict__ rowptr,
                                                     int* __restrict__ cursor) {
    __shared__ int ws[16];
    int lane = threadIdx.x & 63;
    int wid = threadIdx.x >> 6;
    int i = blockIdx.x * SCAN_B + threadIdx.x;
    int c = (i < N_NODES) ? cnt[i] : 0;
    int v = c;
#pragma unroll
    for (int off = 1; off < 64; off <<= 1) {
        int t = __shfl_up(v, off, 64);
        if (lane >= off) v += t;
    }
    if (lane == 63) ws[wid] = v;
    __syncthreads();
    int woff = 0;
    for (int w = 0; w < wid; ++w) woff += ws[w];
    int excl = bsum[blockIdx.x] + woff + v - c;
    if (i < N_NODES) { rowptr[i] = excl; cursor[i] = excl; }
}

// ---- windowed CSR fill: pass p handles dst in [lo, lo+WIN) --------------
__global__ void fill_csr_pass(const int* __restrict__ src32,
                              const int* __restrict__ dst32,
                              int* __restrict__ cursor, int* __restrict__ colidx,
                              int lo) {
    int i = blockIdx.x * blockDim.x + threadIdx.x;
    if (i < N_EDGES) {
        int d = dst32[i];
        if ((unsigned)(d - lo) < (unsigned)WIN) {
            int pos = atomicAdd(&cursor[d], 1);
            colidx[pos] = src32[i];
        }
    }
}

// ---- weight transpose (dtype-aware) -------------------------------------
__global__ void transpose_w(const void* __restrict__ W, u16* __restrict__ Wt,
                            const int* __restrict__ flags) {
    int n = blockIdx.x;
    int k = threadIdx.x;
    float v = flags[0] ? ((const float*)W)[k * DIM + n]
                       : bf2f(((const u16*)W)[k * DIM + n]);
    Wt[n * DIM + k] = f2bf(sane(v));
}

// ---- dense GEMM: register-resident B, dis-prescaled output --------------
// out[row] = bf16( dis[row] * (A[row] @ W) )  -- the pre-scale folds the
// per-edge dis[src] gather out of the aggregate inner loop entirely.
__global__ __launch_bounds__(256) void gemm_mfma(const u16* __restrict__ A,
                                                 const u16* __restrict__ Wt,
                                                 const float* __restrict__ dis,
                                                 u16* __restrict__ out) {
    int w = threadIdx.x >> 6;   // col-group 0..3
    int lane = threadIdx.x & 63;
    int rt = blockIdx.x;        // row tile (100000/16 = 6250 exact)
    int m = lane & 15;
    int quad = lane >> 4;

    bf16x8 B[4][8];
#pragma unroll
    for (int t2 = 0; t2 < 4; ++t2)
#pragma unroll
        for (int ks = 0; ks < 8; ++ks)
            B[t2][ks] = *(const bf16x8*)(Wt + (size_t)((w * 4 + t2) * 16 + m) * DIM +
                                         ks * 32 + quad * 8);

    const u16* arow = A + (size_t)(rt * 16 + m) * DIM + quad * 8;
    f32x4 acc[4];
#pragma unroll
    for (int t2 = 0; t2 < 4; ++t2) acc[t2] = (f32x4){0.f, 0.f, 0.f, 0.f};

#pragma unroll
    for (int ks = 0; ks < 8; ++ks) {
        bf16x8 a = *(const bf16x8*)(arow + ks * 32);
#pragma unroll
        for (int t2 = 0; t2 < 4; ++t2)
            acc[t2] = __builtin_amdgcn_mfma_f32_16x16x32_bf16(a, B[t2][ks], acc[t2], 0, 0, 0);
    }

    // rows owned by this thread: rt*16 + quad*4 + r, r=0..3
    float4 dv = *(const float4*)(dis + rt * 16 + quad * 4);
    float dr[4] = {dv.x, dv.y, dv.z, dv.w};

#pragma unroll
    for (int t2 = 0; t2 < 4; ++t2) {
#pragma unroll
        for (int r = 0; r < 4; ++r) {
            int row = rt * 16 + quad * 4 + r;
            int c = w * 64 + t2 * 16 + m;
            out[(size_t)row * DIM + c] = f2bf(sane(acc[t2][r] * dr[r]));
        }
    }
}

// ---- aggregation + bias + ELU -------------------------------------------
// xw is pre-scaled by dis[src]; inner loop is pure gather+add.
// Wave = 1 node; 2 lane-halves process 2 edges per gather instruction with
// 16B loads (32 lanes x 16B = one 512B row per half). Per 8 edges:
// 1 broadcast int4 colidx load per half + 4 row gathers (5 VMEM instrs).
__global__ __launch_bounds__(256) void aggregate(const u16* __restrict__ xw,
                                                 const int* __restrict__ rowptr,
                                                 const int* __restrict__ colidx,
                                                 const float* __restrict__ dis,
                                                 const void* __restrict__ bias,
                                                 void* __restrict__ out,
                                                 const int* __restrict__ flags,
                                                 int final_layer) {
    int wid = threadIdx.x >> 6;
    int lane = threadIdx.x & 63;
    int node = blockIdx.x * 4 + wid;
    if (node >= N_NODES) return;
    int h = lane >> 5;          // half id: 0 -> even edge group, 1 -> odd
    int c8 = (lane & 31) * 8;   // 8-column base owned by this lane
    const u16* base = xw + c8;

    float2 a0 = make_float2(0.f, 0.f), a1 = a0, a2 = a0, a3 = a0;
    if (h == 0) {  // self term (xw already carries dis[node]) counted once
        uint4 v = *(const uint4*)(base + (size_t)node * DIM);
        a0 = cvt2(v.x); a1 = cvt2(v.y); a2 = cvt2(v.z); a3 = cvt2(v.w);
    }

#define ACC4(v)                                                   \
    do {                                                          \
        float2 t0 = cvt2((v).x), t1 = cvt2((v).y);                \
        float2 t2 = cvt2((v).z), t3 = cvt2((v).w);                \
        a0.x += t0.x; a0.y += t0.y; a1.x += t1.x; a1.y += t1.y;   \
        a2.x += t2.x; a2.y += t2.y; a3.x += t3.x; a3.y += t3.y;   \
    } while (0)

    int beg = rowptr[node];
    int end = rowptr[node + 1];
    int e = beg;

    // peel to 4-edge alignment so main-loop int4 colidx loads are 16B-aligned
    int pe = (beg + 3) & ~3;
    if (pe > end) pe = end;
    for (int t = e; t < pe; t += 2) {
        int idx = t + h;
        if (idx < pe) {
            int s = colidx[idx];
            uint4 v = *(const uint4*)(base + (size_t)s * DIM);
            ACC4(v);
        }
    }
    e = pe;

    int me = e + ((end - e) & ~7);
    int h4 = h * 4;
    for (; e < me; e += 8) {
        int4 c4 = *(const int4*)(colidx + e + h4);  // broadcast within half
        uint4 v0 = *(const uint4*)(base + (size_t)c4.x * DIM);
        uint4 v1 = *(const uint4*)(base + (size_t)c4.y * DIM);
        uint4 v2 = *(const uint4*)(base + (size_t)c4.z * DIM);
        uint4 v3 = *(const uint4*)(base + (size_t)c4.w * DIM);
        ACC4(v0); ACC4(v1); ACC4(v2); ACC4(v3);
    }

    for (; e < end; e += 2) {
        int idx = e + h;
        if (idx < end) {
            int s = colidx[idx];
            uint4 v = *(const uint4*)(base + (size_t)s * DIM);
            ACC4(v);
        }
    }
#undef ACC4

    // combine the two halves (each col summed across both edge groups)
    a0.x += __shfl_xor(a0.x, 32); a0.y += __shfl_xor(a0.y, 32);
    a1.x += __shfl_xor(a1.x, 32); a1.y += __shfl_xor(a1.y, 32);
    a2.x += __shfl_xor(a2.x, 32); a2.y += __shfl_xor(a2.y, 32);
    a3.x += __shfl_xor(a3.x, 32); a3.y += __shfl_xor(a3.y, 32);

    // low half stores cols c8+0..3 (a0,a1), high half c8+4..7 (a2,a3)
    float s0, s1, s2, s3;
    if (h == 0) { s0 = a0.x; s1 = a0.y; s2 = a1.x; s3 = a1.y; }
    else        { s0 = a2.x; s1 = a2.y; s2 = a3.x; s3 = a3.y; }
    int c0 = c8 + h * 4;

    float dn = dis[node];
    float b0, b1, b2, b3;
    int f32mode = flags[0];
    if (f32mode) {
        float4 bv = *(const float4*)((const float*)bias + c0);
        b0 = bv.x; b1 = bv.y; b2 = bv.z; b3 = bv.w;
    } else {
        ushort4 bv = *(const ushort4*)((const u16*)bias + c0);
        b0 = bf2f(bv.x); b1 = bf2f(bv.y); b2 = bf2f(bv.z); b3 = bf2f(bv.w);
    }
    float o0 = dn * s0 + b0;
    float o1 = dn * s1 + b1;
    float o2 = dn * s2 + b2;
    float o3 = dn * s3 + b3;
    o0 = sane(o0 > 0.f ? o0 : expm1f(o0));
    o1 = sane(o1 > 0.f ? o1 : expm1f(o1));
    o2 = sane(o2 > 0.f ? o2 : expm1f(o2));
    o3 = sane(o3 > 0.f ? o3 : expm1f(o3));
    if (final_layer && f32mode) {
        float4 ov; ov.x = o0; ov.y = o1; ov.z = o2; ov.w = o3;
        *(float4*)((float*)out + (size_t)node * DIM + c0) = ov;
    } else {
        ushort4 ov;
        ov.x = f2bf(o0); ov.y = f2bf(o1); ov.z = f2bf(o2); ov.w = f2bf(o3);
        *(ushort4*)((u16*)out + (size_t)node * DIM + c0) = ov;
    }
}

// ---- launch -------------------------------------------------------------
extern "C" void kernel_launch(void* const* d_in, const int* in_sizes, int n_in,
                              void* d_out, int out_size, void* d_ws, size_t ws_size,
                              hipStream_t stream) {
    const void* x  = d_in[0];
    const int*  ei = (const int*)d_in[1];
    const void* W1 = d_in[2];
    const void* b1 = d_in[3];
    const void* W2 = d_in[4];
    const void* b2 = d_in[5];

    char* ws = (char*)d_ws;
    size_t off = 0;
    auto alloc = [&](size_t bytes) {
        void* p = ws + off;
        off = (off + bytes + 255) & ~(size_t)255;
        return p;
    };
    int*   flags    = (int*)alloc(256);
    int*   rowcount = (int*)alloc((size_t)N_NODES * 4);
    int*   rowptr   = (int*)alloc((size_t)(N_NODES + 1) * 4);
    int*   cursor   = (int*)alloc((size_t)N_NODES * 4);
    int*   colidx   = (int*)alloc((size_t)N_EDGES * 4);
    float* dis      = (float*)alloc((size_t)N_NODES * 4);
    int*   bsum     = (int*)alloc((size_t)SCAN_NBLK * 4 + 256);
    u16*   Wt       = (u16*)alloc((size_t)DIM * DIM * 2);
    u16*   xw       = (u16*)alloc((size_t)N_NODES * DIM * 2);
    (void)ws_size;

    // src32/dst32 alias the xw region: their lifetime (count_convert..fill
    // passes) ends before gemm_mfma first writes xw.
    int* src32 = (int*)xw;
    int* dst32 = src32 + N_EDGES;

    u16* xbf = (u16*)d_out;  // d_out doubles as bf16-x scratch, then h

    detect_kernel<<<1, 64, 0, stream>>>((const u32*)x, ei, flags);
    hipMemsetAsync(rowcount, 0, (size_t)N_NODES * 4, stream);
    count_convert<<<(N_EDGES + 255) / 256, 256, 0, stream>>>(ei, rowcount, src32, dst32, flags);
    compute_dis<<<(N_NODES + 255) / 256, 256, 0, stream>>>(rowcount, dis);
    scan_block_sums<<<SCAN_NBLK, SCAN_B, 0, stream>>>(rowcount, bsum);
    scan_bsum<<<1, 128, 0, stream>>>(bsum, rowptr);
    scan_final<<<SCAN_NBLK, SCAN_B, 0, stream>>>(rowcount, bsum, rowptr, cursor);
    for (int p = 0; p < NPASS; ++p)
        fill_csr_pass<<<(N_EDGES + 255) / 256, 256, 0, stream>>>(src32, dst32, cursor,
                                                                 colidx, p * WIN);
    convert_x<<<(N_NODES * DIM + 255) / 256, 256, 0, stream>>>(x, xbf, flags);

    // layer 1
    transpose_w<<<DIM, DIM, 0, stream>>>(W1, Wt, flags);
    gemm_mfma<<<N_NODES / 16, 256, 0, stream>>>(xbf, Wt, dis, xw);
    aggregate<<<N_NODES / 4, 256, 0, stream>>>(xw, rowptr, colidx, dis, b1, d_out, flags, 0);

    // layer 2
    transpose_w<<<DIM, DIM, 0, stream>>>(W2, Wt, flags);
    gemm_mfma<<<N_NODES / 16, 256, 0, stream>>>((const u16*)d_out, Wt, dis, xw);
    aggregate<<<N_NODES / 4, 256, 0, stream>>>(xw, rowptr, colidx, dis, b2, d_out, flags, 1);
}